// Round 9
// baseline (346.627 us; speedup 1.0000x reference)
//
#include <hip/hip_runtime.h>

typedef float f32x4 __attribute__((ext_vector_type(4)));
typedef _Float16 f16x8 __attribute__((ext_vector_type(8)));
typedef _Float16 f16x4 __attribute__((ext_vector_type(4)));
typedef _Float16 f16x2 __attribute__((ext_vector_type(2)));

__device__ __forceinline__ float tanh_fast(float x) {
  float e = __builtin_amdgcn_exp2f(x * 2.885390081777927f);
  return 1.0f - 2.0f * __builtin_amdgcn_rcpf(e + 1.0f);
}

// ---------------------------------------------------------------------------
// Plain transpose + cast fp32 -> f16:  out[C][R] = (f16) in[R][C]
// ---------------------------------------------------------------------------
__global__ __launch_bounds__(256) void k_transpose_cast(
    const float* __restrict__ in, _Float16* __restrict__ outp, int R, int C)
{
  __shared__ float tile[32][33];
  const int tx = threadIdx.x & 31, ty = threadIdx.x >> 5;
  const int tc = blockIdx.x * 32, tr = blockIdx.y * 32;
#pragma unroll
  for (int i = 0; i < 32; i += 8)
    tile[ty + i][tx] = in[(size_t)(tr + ty + i) * C + tc + tx];
  __syncthreads();
#pragma unroll
  for (int i = 0; i < 32; i += 8)
    outp[(size_t)(tc + ty + i) * R + tr + tx] = (_Float16)tile[tx][ty + i];
}

// ---------------------------------------------------------------------------
// GEMM1: xproj[t][b][col] = X[b][t][:] @ Wx[:][col] + bias[col]   (dense!)
// ---------------------------------------------------------------------------
__global__ __launch_bounds__(256) void k_gemm1(
    const float* __restrict__ X, const _Float16* __restrict__ WxT,
    const float* __restrict__ bias, float* __restrict__ xproj)
{
  __shared__ _Float16 As[64][72];
  __shared__ _Float16 Bs[256][72];
  const int tid = threadIdx.x;
  const int lane = tid & 63, w = tid >> 6;
  const int l15 = lane & 15, lq = lane >> 4;
  const int m0 = blockIdx.x * 64;

  f32x4 acc[16];
#pragma unroll
  for (int i = 0; i < 16; ++i) acc[i] = (f32x4){0.f, 0.f, 0.f, 0.f};

  for (int kc = 0; kc < 16; ++kc) {
    const int k0 = kc * 64;
#pragma unroll
    for (int it = 0; it < 4; ++it) {
      int q = tid + it * 256;
      int r = q >> 4, k4 = (q & 15) * 4;
      f32x4 v = *(const f32x4*)(X + (size_t)(m0 + r) * 1024 + k0 + k4);
      f16x4 hv;
      hv[0] = (_Float16)v[0]; hv[1] = (_Float16)v[1];
      hv[2] = (_Float16)v[2]; hv[3] = (_Float16)v[3];
      *(f16x4*)(&As[r][k4]) = hv;
    }
#pragma unroll
    for (int it = 0; it < 8; ++it) {
      int q = tid + it * 256;
      int n = q >> 3, k8 = (q & 7) * 8;
      *(f16x8*)(&Bs[n][k8]) = *(const f16x8*)(WxT + (size_t)n * 1024 + k0 + k8);
    }
    __syncthreads();
    f16x8 a[2];
#pragma unroll
    for (int ks = 0; ks < 2; ++ks)
      a[ks] = *(const f16x8*)(&As[w * 16 + l15][ks * 32 + lq * 8]);
#pragma unroll
    for (int ct = 0; ct < 16; ++ct) {
#pragma unroll
      for (int ks = 0; ks < 2; ++ks) {
        f16x8 bfr = *(const f16x8*)(&Bs[ct * 16 + l15][ks * 32 + lq * 8]);
        acc[ct] = __builtin_amdgcn_mfma_f32_16x16x32_f16(a[ks], bfr, acc[ct], 0, 0, 0);
      }
    }
    __syncthreads();
  }
#pragma unroll
  for (int ct = 0; ct < 16; ++ct) {
    int ncol = ct * 16 + l15;
    float bvv = bias[ncol];
#pragma unroll
    for (int r = 0; r < 4; ++r) {
      int m = m0 + w * 16 + lq * 4 + r;     // m = b*512 + t
      int tt = m & 511, bb = m >> 9;
      xproj[((size_t)tt * 32 + bb) * 256 + ncol] = acc[ct][r] + bvv;
    }
  }
}

// ---------------------------------------------------------------------------
// RNN scan, 16-wave pipe-fill version:
//  - 8 blocks x 4 batches; 16 waves x 16 cols (4 waves/SIMD): deep cross-wave
//    overlap hides per-wave tails/read-heads under other waves' MFMA bursts
//  - one output col per thread: tail = 12 add + 3 cndmask + 1 tanh + 1 cvt
//    + 1 ds_write_b16 + 1 global b16
//  - A rows = h[row&3] broadcast; C component r = batch r; pick batch lq
//  - h LDS [batch][physcol dup x2] stride 1056 B (2-way bank spread, free);
//    8 per-ordinal read offsets in VGPRs, slice rotation (w+i)&7
//  - no k-permutation anywhere (plain layouts end to end)
//  - one raw barrier + lgkmcnt(0) per step; xp prefetched 2 steps
// ---------------------------------------------------------------------------
__global__ __launch_bounds__(1024, 1) void k_scan(
    const float* __restrict__ xproj,      // [512][32][256] fp32 dense
    const _Float16* __restrict__ WhT,     // [256][256] plain transpose
    _Float16* __restrict__ Yt,            // [512][32][256] f16
    float* __restrict__ hT)               // [32][256] fp32
{
  __shared__ char hbuf[2][4224];          // [buf][batch(4) x 1056B (512 data + 512 dup + 32 pad)]
  const int tid = threadIdx.x;
  const int lane = tid & 63, w = tid >> 6;     // w = 0..15
  const int l15 = lane & 15, lq = lane >> 4;
  const int g = blockIdx.x;                    // batches g*4 .. g*4+3
  const int col = w * 16 + l15;

  for (int i = tid; i < 2112; i += 1024) ((float*)hbuf)[i] = 0.f;

  // B fragments, rotated slice order: ord i -> slice ks=(w+i)&7
  f16x8 bf[8];
#pragma unroll
  for (int i = 0; i < 8; ++i) {
    int ks = (w + i) & 7;
    bf[i] = *(const f16x8*)(WhT + (size_t)col * 256 + ks * 32 + lq * 8);
  }

  char* hz = (char*)&hbuf[0][0];
  // per-ordinal read offsets (batch row l15&3, slice (w+i)&7, k-sub lq)
  int ro[8];
#pragma unroll
  for (int i = 0; i < 8; ++i)
    ro[i] = (l15 & 3) * 1056 + ((w + i) & 7) * 64 + lq * 16;
  // write offset: batch lq, this thread's col (data + dup copy at +512)
  const int wo = lq * 1056 + col * 2;
  const bool m1 = (lq & 1) != 0, m2 = (lq & 2) != 0;

  const float* xpb = xproj + (size_t)(g * 4 + lq) * 256 + col;
  _Float16* yb = Yt + (size_t)(g * 4 + lq) * 256 + col;

  __syncthreads();

  float x0 = xpb[0];
  float x1 = xpb[8192];

#define SCAN_STEP(T, CUR, X, LAST)                                             \
  {                                                                            \
    const int t = (T);                                                         \
    f16x8 af[8];                                                               \
    _Pragma("unroll")                                                          \
    for (int i = 0; i < 8; ++i)                                                \
      af[i] = *(const f16x8*)(hz + ro[i] + (CUR) * 4224);                      \
    float xcur = X;                                                            \
    f32x4 acc[4];                                                              \
    _Pragma("unroll")                                                          \
    for (int c = 0; c < 4; ++c) {                                              \
      f32x4 zz = {0.f, 0.f, 0.f, 0.f};                                         \
      acc[c] = __builtin_amdgcn_mfma_f32_16x16x32_f16(af[2 * c], bf[2 * c], zz, 0, 0, 0); \
    }                                                                          \
    { /* refill X for t+2 */                                                   \
      int tn = t + 2; if (tn > 511) tn = 511;                                  \
      X = xpb[(size_t)tn * 8192];                                              \
    }                                                                          \
    _Pragma("unroll")                                                          \
    for (int c = 0; c < 4; ++c)                                                \
      acc[c] = __builtin_amdgcn_mfma_f32_16x16x32_f16(af[2 * c + 1], bf[2 * c + 1], acc[c], 0, 0, 0); \
    f32x4 s = (acc[0] + acc[1]) + (acc[2] + acc[3]);                           \
    float t0s = m1 ? s[1] : s[0];                                              \
    float t1s = m1 ? s[3] : s[2];                                              \
    float v = tanh_fast((m2 ? t1s : t0s) + xcur);                              \
    _Float16 h1 = (_Float16)v;                                                 \
    *(_Float16*)(hz + wo + ((CUR) ^ 1) * 4224) = h1;                           \
    *(_Float16*)(hz + wo + ((CUR) ^ 1) * 4224 + 512) = h1;                     \
    yb[(size_t)t * 8192] = h1;                                                 \
    if (LAST) hT[(size_t)(g * 4 + lq) * 256 + col] = v;                        \
    asm volatile("s_waitcnt lgkmcnt(0)" ::: "memory");                         \
    __builtin_amdgcn_s_barrier();                                              \
    asm volatile("" ::: "memory");                                             \
  }

  SCAN_STEP(0, 0, x0, 0)
  for (int tp = 0; tp < 255; ++tp) {
    SCAN_STEP(2 * tp + 1, 1, x1, 0)
    SCAN_STEP(2 * tp + 2, 0, x0, 0)
  }
  SCAN_STEP(511, 1, x1, 1)
#undef SCAN_STEP
}

// ---------------------------------------------------------------------------
// GEMM3 + fused softmax: out = softmax(Y @ Wd + bd)   (plain k-order)
// ---------------------------------------------------------------------------
__global__ __launch_bounds__(512) void k_gemm3(
    const _Float16* __restrict__ Yt,    // [512][32][256]
    const _Float16* __restrict__ WdT,   // [1024][256]
    const float* __restrict__ bd,       // [1024]
    float* __restrict__ out)            // [16384][1024]
{
  __shared__ _Float16 As[16][264];
  __shared__ _Float16 Bs[128][264];
  __shared__ _Float16 lg[16][1040];
  const int tid = threadIdx.x;
  const int lane = tid & 63, w = tid >> 6;
  const int l15 = lane & 15, lq = lane >> 4;
  const int m0 = blockIdx.x * 16;
  const int b = m0 >> 9, t0 = m0 & 511;

  {
    int r = tid >> 5, k8 = (tid & 31) * 8;
    *(f16x8*)(&As[r][k8]) = *(const f16x8*)(Yt + ((size_t)(t0 + r) * 32 + b) * 256 + k8);
  }
  __syncthreads();
  f16x8 a[8];
#pragma unroll
  for (int ks = 0; ks < 8; ++ks)
    a[ks] = *(const f16x8*)(&As[l15][ks * 32 + lq * 8]);

  for (int cc = 0; cc < 8; ++cc) {
    const int c0 = cc * 128;
    __syncthreads();
#pragma unroll
    for (int i = 0; i < 8; ++i) {
      int q = i * 512 + tid;
      int n = q >> 5, k8 = (q & 31) * 8;
      *(f16x8*)(&Bs[n][k8]) = *(const f16x8*)(WdT + (size_t)(c0 + n) * 256 + k8);
    }
    __syncthreads();
    int ncol = c0 + w * 16 + l15;
    f32x4 acc = {0.f, 0.f, 0.f, 0.f};
#pragma unroll
    for (int ks = 0; ks < 8; ++ks) {
      f16x8 bfr = *(const f16x8*)(&Bs[w * 16 + l15][ks * 32 + lq * 8]);
      acc = __builtin_amdgcn_mfma_f32_16x16x32_f16(a[ks], bfr, acc, 0, 0, 0);
    }
    float bvv = bd[ncol];
#pragma unroll
    for (int r = 0; r < 4; ++r)
      lg[lq * 4 + r][ncol] = (_Float16)(acc[r] + bvv);
  }
  __syncthreads();

  const int row = tid >> 5, j = tid & 31;
  float mx = -1e30f;
#pragma unroll
  for (int k = 0; k < 32; ++k)
    mx = fmaxf(mx, (float)lg[row][j + k * 32]);
#pragma unroll
  for (int m = 1; m < 32; m <<= 1)
    mx = fmaxf(mx, __shfl_xor(mx, m, 64));
  float s = 0.f;
#pragma unroll
  for (int k = 0; k < 32; ++k)
    s += __builtin_amdgcn_exp2f(((float)lg[row][j + k * 32] - mx) * 1.44269504088896f);
#pragma unroll
  for (int m = 1; m < 32; m <<= 1)
    s += __shfl_xor(s, m, 64);
  const float rinv = __builtin_amdgcn_rcpf(s);
  float* orow = out + (size_t)(m0 + row) * 1024;
#pragma unroll
  for (int k = 0; k < 8; ++k) {
    int c = k * 128 + j * 4;
    f32x4 vv;
#pragma unroll
    for (int u = 0; u < 4; ++u)
      vv[u] = __builtin_amdgcn_exp2f(((float)lg[row][c + u] - mx) * 1.44269504088896f) * rinv;
    *(f32x4*)(orow + c) = vv;
  }
}

// ---------------------------------------------------------------------------
extern "C" void kernel_launch(void* const* d_in, const int* in_sizes, int n_in,
                              void* d_out, int out_size, void* d_ws, size_t ws_size,
                              hipStream_t stream) {
  const float* X  = (const float*)d_in[0];
  const float* Wx = (const float*)d_in[1];
  const float* Wh = (const float*)d_in[2];
  const float* bv = (const float*)d_in[3];
  const float* Wd = (const float*)d_in[4];
  const float* bd = (const float*)d_in[5];
  float* out = (float*)d_out;

  char* ws = (char*)d_ws;
  float*    xproj = (float*)(ws);                                  // 16 MB
  _Float16* Yt    = (_Float16*)(ws + (16u << 20));                 // 8 MB
  _Float16* WxT   = (_Float16*)(ws + (24u << 20));                 // 512 KB
  _Float16* WhT   = (_Float16*)(ws + (24u << 20) + (512u << 10));  // 128 KB
  _Float16* WdT   = (_Float16*)(ws + (24u << 20) + (640u << 10));  // 512 KB

  k_transpose_cast<<<dim3(8, 32), 256, 0, stream>>>(Wx, WxT, 1024, 256);
  k_transpose_cast<<<dim3(8, 8),  256, 0, stream>>>(Wh, WhT, 256, 256);
  k_transpose_cast<<<dim3(32, 8), 256, 0, stream>>>(Wd, WdT, 256, 1024);
  k_gemm1<<<dim3(256), 256, 0, stream>>>(X, WxT, bv, xproj);
  k_scan<<<dim3(8), 1024, 0, stream>>>(xproj, WhT, Yt, out + 16384 * 1024);
  k_gemm3<<<dim3(1024), 512, 0, stream>>>(Yt, WdT, bd, out);
}

// Round 10
// 321.332 us; speedup vs baseline: 1.0787x; 1.0787x over previous
//
#include <hip/hip_runtime.h>

typedef float f32x4 __attribute__((ext_vector_type(4)));
typedef float f32x2 __attribute__((ext_vector_type(2)));
typedef _Float16 f16x8 __attribute__((ext_vector_type(8)));
typedef _Float16 f16x4 __attribute__((ext_vector_type(4)));
typedef _Float16 f16x2 __attribute__((ext_vector_type(2)));

__device__ __forceinline__ float tanh_fast(float x) {
  float e = __builtin_amdgcn_exp2f(x * 2.885390081777927f);
  return 1.0f - 2.0f * __builtin_amdgcn_rcpf(e + 1.0f);
}

// ---------------------------------------------------------------------------
// Plain transpose + cast fp32 -> f16:  out[C][R] = (f16) in[R][C]
// ---------------------------------------------------------------------------
__global__ __launch_bounds__(256) void k_transpose_cast(
    const float* __restrict__ in, _Float16* __restrict__ outp, int R, int C)
{
  __shared__ float tile[32][33];
  const int tx = threadIdx.x & 31, ty = threadIdx.x >> 5;
  const int tc = blockIdx.x * 32, tr = blockIdx.y * 32;
#pragma unroll
  for (int i = 0; i < 32; i += 8)
    tile[ty + i][tx] = in[(size_t)(tr + ty + i) * C + tc + tx];
  __syncthreads();
#pragma unroll
  for (int i = 0; i < 32; i += 8)
    outp[(size_t)(tc + ty + i) * R + tr + tx] = (_Float16)tile[tx][ty + i];
}

// ---------------------------------------------------------------------------
// Permuted transpose + cast: out[c][pinv(r)] = (f16) in[r][c]
// pinv(r) = (r&~31) | ((r&15)<<1) | ((r>>4)&1)    (32-block k-permutation)
// ---------------------------------------------------------------------------
__global__ __launch_bounds__(256) void k_transpose_cast_perm(
    const float* __restrict__ in, _Float16* __restrict__ outp, int R, int C)
{
  __shared__ float tile[32][33];
  const int tx = threadIdx.x & 31, ty = threadIdx.x >> 5;
  const int tc = blockIdx.x * 32, tr = blockIdx.y * 32;
#pragma unroll
  for (int i = 0; i < 32; i += 8)
    tile[ty + i][tx] = in[(size_t)(tr + ty + i) * C + tc + tx];
  __syncthreads();
  const int r = tr + tx;
  const int p = (r & ~31) | ((r & 15) << 1) | ((r >> 4) & 1);
#pragma unroll
  for (int i = 0; i < 32; i += 8)
    outp[(size_t)(tc + ty + i) * R + p] = (_Float16)tile[tx][ty + i];
}

// ---------------------------------------------------------------------------
// GEMM1: xproj = X @ Wx + b, scattered into the scan's packed layout.
// BM=32 -> 512 blocks (2/CU, 42KB LDS) for cross-block latency hiding.
//   idx = ((t*8 + g)*8 + w)*128 + (lq*16 + i)*2 + j
//   where batch = g*4 + lq, col = w*32 + j*16 + i
// ---------------------------------------------------------------------------
__global__ __launch_bounds__(256) void k_gemm1(
    const float* __restrict__ X, const _Float16* __restrict__ WxT,
    const float* __restrict__ bias, float* __restrict__ xp_packed)
{
  __shared__ _Float16 As[32][72];
  __shared__ _Float16 Bs[256][72];
  const int tid = threadIdx.x;
  const int lane = tid & 63, w = tid >> 6;
  const int l15 = lane & 15, lq = lane >> 4;
  const int m0 = blockIdx.x * 32;
  const int wm = w & 1, wn = w >> 1;     // m-tile, n-group (128 cols)

  f32x4 acc[8];
#pragma unroll
  for (int i = 0; i < 8; ++i) acc[i] = (f32x4){0.f, 0.f, 0.f, 0.f};

  for (int kc = 0; kc < 16; ++kc) {
    const int k0 = kc * 64;
#pragma unroll
    for (int it = 0; it < 2; ++it) {
      int q = tid + it * 256;            // 0..511
      int r = q >> 4, k4 = (q & 15) * 4;
      f32x4 v = *(const f32x4*)(X + (size_t)(m0 + r) * 1024 + k0 + k4);
      f16x4 hv;
      hv[0] = (_Float16)v[0]; hv[1] = (_Float16)v[1];
      hv[2] = (_Float16)v[2]; hv[3] = (_Float16)v[3];
      *(f16x4*)(&As[r][k4]) = hv;
    }
#pragma unroll
    for (int it = 0; it < 8; ++it) {
      int q = tid + it * 256;
      int n = q >> 3, k8 = (q & 7) * 8;
      *(f16x8*)(&Bs[n][k8]) = *(const f16x8*)(WxT + (size_t)n * 1024 + k0 + k8);
    }
    __syncthreads();
    f16x8 a[2];
#pragma unroll
    for (int ks = 0; ks < 2; ++ks)
      a[ks] = *(const f16x8*)(&As[wm * 16 + l15][ks * 32 + lq * 8]);
#pragma unroll
    for (int ct = 0; ct < 8; ++ct) {
#pragma unroll
      for (int ks = 0; ks < 2; ++ks) {
        f16x8 bfr = *(const f16x8*)(&Bs[wn * 128 + ct * 16 + l15][ks * 32 + lq * 8]);
        acc[ct] = __builtin_amdgcn_mfma_f32_16x16x32_f16(a[ks], bfr, acc[ct], 0, 0, 0);
      }
    }
    __syncthreads();
  }
#pragma unroll
  for (int ct = 0; ct < 8; ++ct) {
    int ncol = wn * 128 + ct * 16 + l15;
    float bvv = bias[ncol];
    int w_s = ncol >> 5, j_s = (ncol >> 4) & 1, i_s = ncol & 15;
#pragma unroll
    for (int r = 0; r < 4; ++r) {
      int m = m0 + wm * 16 + lq * 4 + r;  // m = b*512 + t
      int tt = m & 511, bb = m >> 9;
      int g_s = bb >> 2, lq_s = bb & 3;
      size_t idx = (((size_t)tt * 8 + g_s) * 8 + w_s) * 128 + (lq_s * 16 + i_s) * 2 + j_s;
      xp_packed[idx] = acc[ct][r] + bvv;
    }
  }
}

// ---------------------------------------------------------------------------
// RNN scan (R7 champion, verbatim): 8 blocks x 4 batches; 8 waves x 32 cols.
// ---------------------------------------------------------------------------
__global__ __launch_bounds__(512, 2) void k_scan(
    const float* __restrict__ xp_packed,
    const _Float16* __restrict__ WhTp,    // [256 col][256 phys-k] permuted
    _Float16* __restrict__ Yt,            // [512][32][256 phys] f16
    float* __restrict__ hT)               // [32][256] fp32 (logical cols)
{
  __shared__ char hbuf[2][4224];
  const int tid = threadIdx.x;
  const int lane = tid & 63, w = tid >> 6;     // w = 0..7
  const int l15 = lane & 15, lq = lane >> 4;
  const int g = blockIdx.x;

  for (int i = tid; i < 2112; i += 512) ((float*)hbuf)[i] = 0.f;

  f16x8 bf[2][8];
#pragma unroll
  for (int j = 0; j < 2; ++j)
#pragma unroll
    for (int i = 0; i < 8; ++i) {
      int ks = (w + i) & 7;
      bf[j][i] = *(const f16x8*)(WhTp + (w * 32 + j * 16 + l15) * 256 + ks * 32 + lq * 8);
    }

  char* hz = (char*)&hbuf[0][0];
  const int rd_base = (l15 & 3) * 1056 + w * 64 + lq * 16;
  const int wr_base = lq * 1056 + w * 64 + l15 * 4;
  const bool m1 = (lq & 1) != 0, m2 = (lq & 2) != 0;

  const float* xpb = xp_packed + ((size_t)g * 8 + w) * 128 + lane * 2;
  _Float16* yb = Yt + ((size_t)(g * 4 + lq)) * 256 + w * 32 + l15 * 2;
  float* hTb = hT + (g * 4 + lq) * 256 + w * 32 + l15;

  __syncthreads();

  f32x2 x0 = *(const f32x2*)(xpb);
  f32x2 x1 = *(const f32x2*)(xpb + 8192);

#define SCAN_STEP(T, CUR, X, LAST)                                             \
  {                                                                            \
    const int t = (T);                                                         \
    f16x8 af[8];                                                               \
    af[0] = *(const f16x8*)(hz + rd_base + (CUR) * 4224 + 0 * 64);             \
    asm volatile("" ::: "memory");                                             \
    __builtin_amdgcn_s_barrier();                                              \
    asm volatile("" ::: "memory");                                             \
    _Pragma("unroll")                                                          \
    for (int i = 1; i < 8; ++i)                                                \
      af[i] = *(const f16x8*)(hz + rd_base + (CUR) * 4224 + i * 64);           \
    f32x2 xcur = X;                                                            \
    f32x4 acc[2][4];                                                           \
    _Pragma("unroll")                                                          \
    for (int j = 0; j < 2; ++j) {                                              \
      _Pragma("unroll")                                                        \
      for (int c = 0; c < 4; ++c) {                                            \
        f32x4 zz = {0.f, 0.f, 0.f, 0.f};                                       \
        acc[j][c] = __builtin_amdgcn_mfma_f32_16x16x32_f16(af[2 * c], bf[j][2 * c], zz, 0, 0, 0); \
      }                                                                        \
    }                                                                          \
    { /* refill X for t+2 */                                                   \
      int tn = t + 2; if (tn > 511) tn = 511;                                  \
      X = *(const f32x2*)(xpb + (size_t)tn * 8192);                            \
    }                                                                          \
    _Pragma("unroll")                                                          \
    for (int j = 0; j < 2; ++j) {                                              \
      _Pragma("unroll")                                                        \
      for (int c = 0; c < 4; ++c)                                              \
        acc[j][c] = __builtin_amdgcn_mfma_f32_16x16x32_f16(af[2 * c + 1], bf[j][2 * c + 1], acc[j][c], 0, 0, 0); \
    }                                                                          \
    f16x2 h2;                                                                  \
    float vv[2];                                                               \
    _Pragma("unroll")                                                          \
    for (int j = 0; j < 2; ++j) {                                              \
      f32x4 s01 = acc[j][0] + acc[j][1];                                       \
      f32x4 s23 = acc[j][2] + acc[j][3];                                       \
      f32x4 s = s01 + s23;                                                     \
      float t0 = m1 ? s[1] : s[0];                                             \
      float t1 = m1 ? s[3] : s[2];                                             \
      float v = tanh_fast((m2 ? t1 : t0) + xcur[j]);                           \
      vv[j] = v;                                                               \
      h2[j] = (_Float16)v;                                                     \
    }                                                                          \
    *(f16x2*)(hz + wr_base + ((CUR) ^ 1) * 4224) = h2;                         \
    *(f16x2*)(hz + wr_base + ((CUR) ^ 1) * 4224 + 512) = h2;                   \
    *(f16x2*)(yb + (size_t)t * 8192) = h2;                                     \
    if (LAST) {                                                                \
      hTb[0] = vv[0];                                                          \
      hTb[16] = vv[1];                                                         \
    }                                                                          \
    asm volatile("s_waitcnt lgkmcnt(0)" ::: "memory");                         \
  }

  SCAN_STEP(0, 0, x0, 0)
  for (int tp = 0; tp < 255; ++tp) {
    SCAN_STEP(2 * tp + 1, 1, x1, 0)
    SCAN_STEP(2 * tp + 2, 0, x0, 0)
  }
  SCAN_STEP(511, 1, x1, 1)
#undef SCAN_STEP
}

// ---------------------------------------------------------------------------
// GEMM3 + fused softmax. Half-K B-staging: Bs[128][136] (76.5KB total LDS
// -> 2 blocks/CU for cross-block latency hiding).
// ---------------------------------------------------------------------------
__global__ __launch_bounds__(512) void k_gemm3(
    const _Float16* __restrict__ Yt,    // [512][32][256 phys]
    const _Float16* __restrict__ WdTp,  // [1024][256 phys]
    const float* __restrict__ bd,       // [1024]
    float* __restrict__ out)            // [16384][1024]
{
  __shared__ _Float16 As[16][264];
  __shared__ _Float16 Bs[128][136];
  __shared__ _Float16 lg[16][1040];
  const int tid = threadIdx.x;
  const int lane = tid & 63, w = tid >> 6;
  const int l15 = lane & 15, lq = lane >> 4;
  const int m0 = blockIdx.x * 16;
  const int b = m0 >> 9, t0 = m0 & 511;

  {
    int r = tid >> 5, k8 = (tid & 31) * 8;
    *(f16x8*)(&As[r][k8]) = *(const f16x8*)(Yt + ((size_t)(t0 + r) * 32 + b) * 256 + k8);
  }
  __syncthreads();
  f16x8 a[8];
#pragma unroll
  for (int ks = 0; ks < 8; ++ks)
    a[ks] = *(const f16x8*)(&As[l15][ks * 32 + lq * 8]);

  for (int cc = 0; cc < 8; ++cc) {
    const int c0 = cc * 128;
    const int ncol = c0 + w * 16 + l15;
    f32x4 acc = {0.f, 0.f, 0.f, 0.f};
    __syncthreads();                     // protect Bs from prior readers
#pragma unroll
    for (int i = 0; i < 4; ++i) {        // stage K-half 0 (128 cols x 128 k)
      int q = i * 512 + tid;
      int n = q >> 4, k8 = (q & 15) * 8;
      *(f16x8*)(&Bs[n][k8]) = *(const f16x8*)(WdTp + (size_t)(c0 + n) * 256 + k8);
    }
    __syncthreads();
#pragma unroll
    for (int ks = 0; ks < 4; ++ks) {
      f16x8 bfr = *(const f16x8*)(&Bs[w * 16 + l15][ks * 32 + lq * 8]);
      acc = __builtin_amdgcn_mfma_f32_16x16x32_f16(a[ks], bfr, acc, 0, 0, 0);
    }
    __syncthreads();
#pragma unroll
    for (int i = 0; i < 4; ++i) {        // stage K-half 1
      int q = i * 512 + tid;
      int n = q >> 4, k8 = (q & 15) * 8;
      *(f16x8*)(&Bs[n][k8]) = *(const f16x8*)(WdTp + (size_t)(c0 + n) * 256 + 128 + k8);
    }
    __syncthreads();
#pragma unroll
    for (int ks = 4; ks < 8; ++ks) {
      f16x8 bfr = *(const f16x8*)(&Bs[w * 16 + l15][(ks - 4) * 32 + lq * 8]);
      acc = __builtin_amdgcn_mfma_f32_16x16x32_f16(a[ks], bfr, acc, 0, 0, 0);
    }
    float bvv = bd[ncol];
#pragma unroll
    for (int r = 0; r < 4; ++r)
      lg[lq * 4 + r][ncol] = (_Float16)(acc[r] + bvv);
  }
  __syncthreads();

  const int row = tid >> 5, j = tid & 31;
  float mx = -1e30f;
#pragma unroll
  for (int k = 0; k < 32; ++k)
    mx = fmaxf(mx, (float)lg[row][j + k * 32]);
#pragma unroll
  for (int m = 1; m < 32; m <<= 1)
    mx = fmaxf(mx, __shfl_xor(mx, m, 64));
  float s = 0.f;
#pragma unroll
  for (int k = 0; k < 32; ++k)
    s += __builtin_amdgcn_exp2f(((float)lg[row][j + k * 32] - mx) * 1.44269504088896f);
#pragma unroll
  for (int m = 1; m < 32; m <<= 1)
    s += __shfl_xor(s, m, 64);
  const float rinv = __builtin_amdgcn_rcpf(s);
  float* orow = out + (size_t)(m0 + row) * 1024;
#pragma unroll
  for (int k = 0; k < 8; ++k) {
    int c = k * 128 + j * 4;
    f32x4 vv;
#pragma unroll
    for (int u = 0; u < 4; ++u)
      vv[u] = __builtin_amdgcn_exp2f(((float)lg[row][c + u] - mx) * 1.44269504088896f) * rinv;
    *(f32x4*)(orow + c) = vv;
  }
}

// ---------------------------------------------------------------------------
extern "C" void kernel_launch(void* const* d_in, const int* in_sizes, int n_in,
                              void* d_out, int out_size, void* d_ws, size_t ws_size,
                              hipStream_t stream) {
  const float* X  = (const float*)d_in[0];
  const float* Wx = (const float*)d_in[1];
  const float* Wh = (const float*)d_in[2];
  const float* bv = (const float*)d_in[3];
  const float* Wd = (const float*)d_in[4];
  const float* bd = (const float*)d_in[5];
  float* out = (float*)d_out;

  char* ws = (char*)d_ws;
  float*    xp_packed = (float*)(ws);                              // 16 MB
  _Float16* Yt    = (_Float16*)(ws + (16u << 20));                 // 8 MB
  _Float16* WxT   = (_Float16*)(ws + (24u << 20));                 // 512 KB
  _Float16* WhTp  = (_Float16*)(ws + (24u << 20) + (512u << 10));  // 128 KB
  _Float16* WdTp  = (_Float16*)(ws + (24u << 20) + (640u << 10));  // 512 KB

  k_transpose_cast<<<dim3(8, 32), 256, 0, stream>>>(Wx, WxT, 1024, 256);
  k_transpose_cast_perm<<<dim3(8, 8),  256, 0, stream>>>(Wh, WhTp, 256, 256);
  k_transpose_cast_perm<<<dim3(32, 8), 256, 0, stream>>>(Wd, WdTp, 256, 1024);
  k_gemm1<<<dim3(512), 256, 0, stream>>>(X, WxT, bv, xp_packed);
  k_scan<<<dim3(8), 512, 0, stream>>>(xp_packed, WhTp, Yt, out + 16384 * 1024);
  k_gemm3<<<dim3(1024), 512, 0, stream>>>(Yt, WdTp, bd, out);
}